// Round 18
// baseline (88.407 us; speedup 1.0000x reference)
//
#include <hip/hip_runtime.h>
#include <math.h>

#define DIM 256

typedef float f32x4 __attribute__((ext_vector_type(4)));
typedef int   i32x8 __attribute__((ext_vector_type(8)));

__constant__ const float kTempInvLog2e = 20.0f * 1.4426950408889634f; // (1/temp)*log2(e)
#define LN2 0.6931471805599453f
#define EPS_NORM 1e-8f
#define SCALE_ONE 0x7F7F7F7Fu   // e8m0 bias-127 in every byte = x1.0

// f32x4 -> 4 packed OCP e4m3 bytes via HW cvt_pk (2 instrs, RNE-sat)
static __device__ inline unsigned f2fp8x4(float4 v, float s) {
    int r = 0;
    r = __builtin_amdgcn_cvt_pk_fp8_f32(v.x * s, v.y * s, r, false); // low word
    r = __builtin_amdgcn_cvt_pk_fp8_f32(v.z * s, v.w * s, r, true);  // high word
    return (unsigned)r;
}

// assemble a 32-byte (8 VGPR) MFMA operand from two 16-B pieces
static __device__ inline i32x8 ld_frag32(const void* p0, const void* p1) {
    uint4 a = *(const uint4*)p0;
    uint4 b = *(const uint4*)p1;
    i32x8 v;
    v[0] = a.x; v[1] = a.y; v[2] = a.z; v[3] = a.w;
    v[4] = b.x; v[5] = b.y; v[6] = b.z; v[7] = b.w;
    return v;
}

// Kernel 1: normalize + fp8-quantize (HW cvt) + PACK for the K=128 scaled-MFMA
// fragment. Also zeroes rowsum[] and out[0] (ws/out must be clean each replay)
// and writes diag[r] (exact fp32). Layout: 16-row tile T, K-chunk kc (128 k
// each); chunk CI = T*2+kc is 2048 B: byte = CI*2048 + piece*1024 + lane*16,
// lane = rowlocal + 16*g, holding X[row][kc*128 + g*32 + piece*16 .. +16].
__global__ __launch_bounds__(256) void normpack_kernel(
    const float* __restrict__ A, const float* __restrict__ B,
    unsigned char* __restrict__ Apk, unsigned char* __restrict__ Bpk,
    float* __restrict__ diag, float* __restrict__ rowsum,
    float* __restrict__ out, int n)
{
    __shared__ uint4 lA[256];
    __shared__ uint4 lB[256];
    const int t = threadIdx.x;
    const int rl = t >> 4;       // row-local 0..15
    const int c16 = t & 15;      // 16-elem chunk: abs k in [16*c16, 16*c16+16)
    const int r = blockIdx.x * 16 + rl;

    if (blockIdx.x == 0 && t == 0) out[0] = 0.0f;  // finale accumulates atomically

    const float4* pa = (const float4*)(A + (size_t)r * DIM + c16 * 16);
    const float4* pb = (const float4*)(B + (size_t)r * DIM + c16 * 16);
    float4 a0 = pa[0], a1 = pa[1], a2 = pa[2], a3 = pa[3];
    float4 b0 = pb[0], b1 = pb[1], b2 = pb[2], b3 = pb[3];

    float ssa = a0.x*a0.x + a0.y*a0.y + a0.z*a0.z + a0.w*a0.w
              + a1.x*a1.x + a1.y*a1.y + a1.z*a1.z + a1.w*a1.w
              + a2.x*a2.x + a2.y*a2.y + a2.z*a2.z + a2.w*a2.w
              + a3.x*a3.x + a3.y*a3.y + a3.z*a3.z + a3.w*a3.w;
    float ssb = b0.x*b0.x + b0.y*b0.y + b0.z*b0.z + b0.w*b0.w
              + b1.x*b1.x + b1.y*b1.y + b1.z*b1.z + b1.w*b1.w
              + b2.x*b2.x + b2.y*b2.y + b2.z*b2.z + b2.w*b2.w
              + b3.x*b3.x + b3.y*b3.y + b3.z*b3.z + b3.w*b3.w;
    float dd  = a0.x*b0.x + a0.y*b0.y + a0.z*b0.z + a0.w*b0.w
              + a1.x*b1.x + a1.y*b1.y + a1.z*b1.z + a1.w*b1.w
              + a2.x*b2.x + a2.y*b2.y + a2.z*b2.z + a2.w*b2.w
              + a3.x*b3.x + a3.y*b3.y + a3.z*b3.z + a3.w*b3.w;
#pragma unroll
    for (int m = 1; m < 16; m <<= 1) {
        ssa += __shfl_xor(ssa, m, 64);
        ssb += __shfl_xor(ssb, m, 64);
        dd  += __shfl_xor(dd, m, 64);
    }
    float na = fmaxf(sqrtf(ssa), EPS_NORM);
    float nb = fmaxf(sqrtf(ssb), EPS_NORM);
    float sa = kTempInvLog2e / na;
    float sb = 1.0f / nb;
    if (c16 == 0) {
        diag[r] = dd / (na * nb) * kTempInvLog2e;
        rowsum[r] = 0.0f;   // init for gemm's atomicAdd (ws is poisoned)
    }

    // kc = c16>>3, g = (c16&7)>>1, piece = c16&1, lane = rl + 16*g
    const int u = ((c16 >> 3) << 7) + ((c16 & 1) << 6) + rl + ((c16 & 7) >> 1) * 16;
    uint4 ga, gb;
    ga.x = f2fp8x4(a0, sa); ga.y = f2fp8x4(a1, sa);
    ga.z = f2fp8x4(a2, sa); ga.w = f2fp8x4(a3, sa);
    gb.x = f2fp8x4(b0, sb); gb.y = f2fp8x4(b1, sb);
    gb.z = f2fp8x4(b2, sb); gb.w = f2fp8x4(b3, sb);
    lA[u] = ga; lB[u] = gb;
    __syncthreads();

    ((uint4*)Apk)[(size_t)blockIdx.x * 256 + t] = lA[t];
    ((uint4*)Bpk)[(size_t)blockIdx.x * 256 + t] = lB[t];
}

// async 16B/lane global->LDS copy (wave-uniform LDS base + lane*16)
static __device__ inline void async_copy16(const void* g, void* l) {
    __builtin_amdgcn_global_load_lds(
        (const __attribute__((address_space(1))) unsigned int*)g,
        (__attribute__((address_space(3))) unsigned int*)l, 16, 0, 0);
}

// Kernel 2: R9/R17 config (16 splits, 512 blocks, 2/CU, 2x8KB LDS dbuf,
// __syncthreads, in-loop afrag pin) + two-stage acc (R15) + FORCED
// INSTRUCTION INTERLEAVE via sched_group_barrier (T19).
// Why: R13 proved the ~1.9us/subtile cost persists in a barrier-free,
// load-free, independent-subtile stream -> dependency stall inside the
// compiler's schedule. R15 changed the DATA graph (two acc sets) but
// nothing forced the EMITTED ORDER — LLVM may cluster exp2 after its own
// tile's MFMAs (register-pressure heuristic), recreating the serial seam.
// sched_group_barrier pins emission: 8x DS_READ, then 16x {1 MFMA, 4 VALU}
// — exp2/sums of tile t-1 threaded BETWEEN tile t's MFMA issues.
__global__ __launch_bounds__(256, 2) void gemm_lse_kernel(
    const unsigned char* __restrict__ Apk, const unsigned char* __restrict__ Bpk,
    float* __restrict__ rowsum, int n)
{
    __shared__ char ldsbuf[16384];   // 2 x 8 KB B-tile double buffer
    const int lane = threadIdx.x & 63;
    const int w = threadIdx.x >> 6;
    const int c = lane & 15;
    const int q = lane >> 4;

    const int i = blockIdx.x;
    const int split = ((i & 7) << 1) | ((i >> 3) & 1);  // 0..15, XCD-pinned
    const int rowblk = i >> 4;                           // 0..31
    const int rowbase = rowblk * 256 + w * 64;

    // A fragments: 4 row-tiles x 2 K-chunks, 32 B/lane each (two 16-B pieces)
    i32x8 afrag[4][2];
#pragma unroll
    for (int m = 0; m < 4; ++m) {
        const int AT = rowblk * 16 + w * 4 + m;
#pragma unroll
        for (int kc = 0; kc < 2; ++kc) {
            const char* base = (const char*)Apk + ((size_t)AT * 2 + kc) * 2048 + lane * 16;
            afrag[m][kc] = ld_frag32(base, base + 1024);
        }
    }

    float sums[16];
#pragma unroll
    for (int s = 0; s < 16; ++s) sums[s] = 0.0f;

    const char* bbase = (const char*)Bpk + (size_t)split * 32 * 4096; // 128 KB slice

    // stage tile 0 into buffer 0 (each wave copies its 2 KB quarter)
    {
        const char* src = bbase + w * 2048 + (size_t)lane * 16;
        char* dst = ldsbuf + w * 2048;
        async_copy16(src, dst);
        async_copy16(src + 1024, dst + 1024);
    }
    __syncthreads();

    f32x4 accA[4][2], accB[4][2];

// issue prefetch of tile IT into LDS buffer BUF (each wave its 2 KB quarter)
#define PREFETCH(IT, BUF) do {                                               \
    const char* _src = bbase + (size_t)(IT) * 8192 + w * 2048 + (size_t)lane * 16; \
    char* _dst = ldsbuf + (BUF) * 8192 + w * 2048;                           \
    async_copy16(_src, _dst);                                                \
    async_copy16(_src + 1024, _dst + 1024);                                  \
} while (0)

// ds_read bfrags from BUF and issue 16 MFMAs into ACC (no consumption of ACC)
#define MFMA_TILE(ACC, BUF) do {                                             \
    _Pragma("unroll") for (int m = 0; m < 4; ++m)                            \
        _Pragma("unroll") for (int kc = 0; kc < 2; ++kc)                     \
            asm volatile("" : "+v"(afrag[m][kc]));  /* keep resident */      \
    const char* _lb = ldsbuf + (BUF) * 8192 + (size_t)lane * 16;             \
    _Pragma("unroll") for (int m = 0; m < 4; ++m)                            \
        _Pragma("unroll") for (int nc = 0; nc < 2; ++nc)                     \
            ACC[m][nc] = (f32x4){0.f, 0.f, 0.f, 0.f};                        \
    _Pragma("unroll") for (int nc = 0; nc < 2; ++nc)                         \
        _Pragma("unroll") for (int kc = 0; kc < 2; ++kc) {                   \
            const char* _p = _lb + nc * 4096 + kc * 2048;                    \
            i32x8 _bf = ld_frag32(_p, _p + 1024);                            \
            _Pragma("unroll") for (int m = 0; m < 4; ++m)                    \
                ACC[m][nc] = __builtin_amdgcn_mfma_scale_f32_16x16x128_f8f6f4( \
                    afrag[m][kc], _bf, ACC[m][nc],                           \
                    0, 0, 0, SCALE_ONE, 0, SCALE_ONE);                       \
        }                                                                    \
} while (0)

// exp2+sum a fully-complete acc set (previous tile)
#define EXP_TILE(ACC) do {                                                   \
    _Pragma("unroll") for (int m = 0; m < 4; ++m)                            \
        _Pragma("unroll") for (int nc = 0; nc < 2; ++nc)                     \
            _Pragma("unroll") for (int r = 0; r < 4; ++r)                    \
                sums[m * 4 + r] += __builtin_amdgcn_exp2f(ACC[m][nc][r]);    \
} while (0)

// pin the region's emission order: 8 ds_read first, then 1 MFMA : 4 VALU
// interleave (VALU = prev tile's exp2/add + acc zero-init). Masks per T19:
// DS_READ=0x100, MFMA=0x8, VALU=0x2.
#define SCHED_PIN() do {                                                     \
    __builtin_amdgcn_sched_group_barrier(0x100, 8, 0);                       \
    _Pragma("unroll") for (int g = 0; g < 16; ++g) {                         \
        __builtin_amdgcn_sched_group_barrier(0x008, 1, 0);                   \
        __builtin_amdgcn_sched_group_barrier(0x002, 4, 0);                   \
    }                                                                        \
} while (0)

    // 16 tiles as 8 even/odd pairs: MFMA(t) interleaved with EXP(t-1)
#pragma unroll 1
    for (int itp = 0; itp < 8; ++itp) {
        // even iteration: tile 2*itp in buf0
        PREFETCH(2 * itp + 1, 1);
        MFMA_TILE(accA, 0);
        if (itp > 0) EXP_TILE(accB);   // tile 2*itp-1, complete 2 barriers ago
        SCHED_PIN();
        __syncthreads();
        // odd iteration: tile 2*itp+1 in buf1
        if (itp < 7) PREFETCH(2 * itp + 2, 0);
        MFMA_TILE(accB, 1);
        EXP_TILE(accA);                // tile 2*itp
        SCHED_PIN();
        __syncthreads();
    }
    EXP_TILE(accB);                    // tile 15

#undef PREFETCH
#undef MFMA_TILE
#undef EXP_TILE
#undef SCHED_PIN

    // reduce row sums across the 16 lanes of each q-group (cols mod 16)
#pragma unroll
    for (int s = 0; s < 16; ++s) {
        float v = sums[s];
        v += __shfl_xor(v, 1, 64);
        v += __shfl_xor(v, 2, 64);
        v += __shfl_xor(v, 4, 64);
        v += __shfl_xor(v, 8, 64);
        sums[s] = v;
    }
    if (c == 0) {
#pragma unroll
        for (int m = 0; m < 4; ++m)
#pragma unroll
            for (int r = 0; r < 4; ++r)
                atomicAdd(&rowsum[rowbase + m * 16 + q * 4 + r], sums[m * 4 + r]);
    }
}

// Kernel 3: PARALLEL finale (R17, measured win) — 32 blocks x 256 thr, one
// row per thread; wave shuffle-reduce + 4-entry LDS combine + one
// atomicAdd(out) per block. out[0] zeroed by normpack.
// loss = (ln2/n) * sum_rows( log2(rowsum[row]) - diag[row] )
__global__ __launch_bounds__(256) void finale_kernel(
    const float* __restrict__ rowsum, const float* __restrict__ diag,
    float* __restrict__ out, int n)
{
    const int t = threadIdx.x;
    const int row = blockIdx.x * 256 + t;
    float local = log2f(rowsum[row]) - diag[row];
#pragma unroll
    for (int m = 1; m < 64; m <<= 1)
        local += __shfl_xor(local, m, 64);
    __shared__ float red[4];
    if ((t & 63) == 0) red[t >> 6] = local;
    __syncthreads();
    if (t == 0)
        atomicAdd(out, (red[0] + red[1] + red[2] + red[3]) * (LN2 / (float)n));
}

extern "C" void kernel_launch(void* const* d_in, const int* in_sizes, int n_in,
                              void* d_out, int out_size, void* d_ws, size_t ws_size,
                              hipStream_t stream) {
    const int n = in_sizes[0] / DIM;  // 8192
    const float* A = (const float*)d_in[0];
    const float* B = (const float*)d_in[1];
    float* out = (float*)d_out;

    // workspace layout
    unsigned char* Apk = (unsigned char*)d_ws;                   // n*DIM fp8 (2 MB)
    unsigned char* Bpk = Apk + (size_t)n * DIM;                  // n*DIM fp8 (2 MB)
    float* rowsum = (float*)(Bpk + (size_t)n * DIM);             // n f32
    float* diag = rowsum + n;                                    // n f32

    normpack_kernel<<<n / 16, 256, 0, stream>>>(A, B, Apk, Bpk, diag, rowsum, out, n);

    // 32 rowblocks x 16 splits (best-measured R9 config), 2 blocks/CU
    gemm_lse_kernel<<<(n / 256) * 16, 256, 0, stream>>>(Apk, Bpk, rowsum, n);

    finale_kernel<<<n / 256, 256, 0, stream>>>(rowsum, diag, out, n);
}